// Round 2
// 11284.139 us; speedup vs baseline: 1.1165x; 1.1165x over previous
//
#include <hip/hip_runtime.h>
#include <hip/hip_bf16.h>

#define B_ 32
#define S_ 128
#define VT_ 32000

typedef __hip_bfloat16 bf16;
typedef short bf16x8 __attribute__((ext_vector_type(8)));
typedef float f32x4 __attribute__((ext_vector_type(4)));

__device__ __forceinline__ float b2f(bf16 v){ return __bfloat162float(v); }
__device__ __forceinline__ float sigf(float x){ return 1.f/(1.f + expf(-x)); }

// ---------------- fp32 -> bf16 weight conversion ---------------------------------
__global__ __launch_bounds__(256) void k_cvt(const float* __restrict__ src,
                                             bf16* __restrict__ dst, int n)
{
    int i = (blockIdx.x*256 + threadIdx.x)*4;
    if (i >= n) return;
    float4 v = *(const float4*)(src + i);
    dst[i+0] = __float2bfloat16(v.x);
    dst[i+1] = __float2bfloat16(v.y);
    dst[i+2] = __float2bfloat16(v.z);
    dst[i+3] = __float2bfloat16(v.w);
}

// ---------------- embed src: encA[s*32+b][256] = src_emb[x[b][s]] ----------------
__global__ __launch_bounds__(256) void k_embed(const int* __restrict__ x,
                                               const float* __restrict__ emb,
                                               float* __restrict__ outA)
{
    int idx = blockIdx.x*256 + threadIdx.x;      // 4096*256 total
    int row = idx >> 8, d = idx & 255;
    int s = row >> 5, bb = row & 31;
    int tok = x[bb*128 + s];
    outA[(size_t)row*256 + d] = emb[(size_t)tok*256 + d];
}

// ---------------- C[dir][row][j] = A[row]@W[dir]^T + b  (fp32 tiled GEMM) --------
// A: [4096][lda] fp32, W: [ndir][N][K] fp32, C: [ndir][4096][N] fp32; bias may be null
__global__ __launch_bounds__(256) void k_xgemm(const float* __restrict__ A, int lda, int K,
                                               const float* __restrict__ W,
                                               const float* __restrict__ bias,
                                               float* __restrict__ C, int N)
{
    int dir = blockIdx.z;
    const float* Wd = W + (size_t)dir*N*K;
    float* Cd = C + (size_t)dir*4096*N;
    __shared__ __align__(16) float As[16][68];
    __shared__ __align__(16) float Ws[16][68];
    int tid = threadIdx.x;
    int m0 = blockIdx.y*64, n0 = blockIdx.x*64;
    int tx = tid & 15, ty = tid >> 4;
    int mr = tid >> 2, kq = tid & 3;
    float acc[4][4];
    #pragma unroll
    for (int i=0;i<4;i++)
        #pragma unroll
        for (int j=0;j<4;j++) acc[i][j] = 0.f;

    for (int k0 = 0; k0 < K; k0 += 16){
        __syncthreads();
        float4 av = *(const float4*)(A + (size_t)(m0+mr)*lda + k0 + kq*4);
        As[kq*4+0][mr] = av.x; As[kq*4+1][mr] = av.y;
        As[kq*4+2][mr] = av.z; As[kq*4+3][mr] = av.w;
        float4 wv = *(const float4*)(Wd + (size_t)(n0+mr)*K + k0 + kq*4);
        Ws[kq*4+0][mr] = wv.x; Ws[kq*4+1][mr] = wv.y;
        Ws[kq*4+2][mr] = wv.z; Ws[kq*4+3][mr] = wv.w;
        __syncthreads();
        #pragma unroll
        for (int k = 0; k < 16; k++){
            float4 aa = *(const float4*)&As[k][tx*4];
            float4 ww = *(const float4*)&Ws[k][ty*4];
            float a4[4] = {aa.x, aa.y, aa.z, aa.w};
            float w4[4] = {ww.x, ww.y, ww.z, ww.w};
            #pragma unroll
            for (int i=0;i<4;i++)
                #pragma unroll
                for (int j=0;j<4;j++) acc[i][j] += a4[i]*w4[j];
        }
    }
    #pragma unroll
    for (int j=0;j<4;j++){
        float bv = bias ? bias[dir*N + n0 + ty*4 + j] : 0.f;
        #pragma unroll
        for (int i=0;i<4;i++)
            Cd[(size_t)(m0+tx*4+i)*N + n0 + ty*4 + j] = acc[i][j] + bv;
    }
}

// ---------------- encoder scan: one WG per (dir,b), full 128-step recurrence -----
__global__ __launch_bounds__(256) void k_encscan(const float* __restrict__ xg,
                                                 const bf16* __restrict__ Whh,
                                                 float* __restrict__ outSeq,
                                                 float* __restrict__ hfin,
                                                 float* __restrict__ cfin)
{
    int blk = blockIdx.x;                 // 64
    int dir = blk >> 5, b = blk & 31;
    int tid = threadIdx.x;                // 256
    const bf16* W = Whh + (size_t)dir*262144;          // 1024*256
    const float* xgd = xg + (size_t)dir*4194304;
    __shared__ __align__(16) float hs[256];
    hs[tid] = 0.f;
    float c = 0.f, hcur = 0.f;
    __syncthreads();
    const bf16* w0 = W + (size_t)tid*256;
    const bf16* w1 = W + (size_t)(256+tid)*256;
    const bf16* w2 = W + (size_t)(512+tid)*256;
    const bf16* w3 = W + (size_t)(768+tid)*256;
    for (int t = 0; t < 128; t++){
        int td = dir ? (127 - t) : t;
        const float* xr = xgd + (size_t)(td*32 + b)*1024;
        float g0 = xr[tid], g1 = xr[256+tid], g2 = xr[512+tid], g3 = xr[768+tid];
        for (int k = 0; k < 256; k += 8){
            float4 h0 = *(const float4*)&hs[k];
            float4 h1 = *(const float4*)&hs[k+4];
            bf16x8 wa = *(const bf16x8*)(w0 + k);
            bf16x8 wb = *(const bf16x8*)(w1 + k);
            bf16x8 wc = *(const bf16x8*)(w2 + k);
            bf16x8 wd = *(const bf16x8*)(w3 + k);
            float hv[8] = {h0.x, h0.y, h0.z, h0.w, h1.x, h1.y, h1.z, h1.w};
            #pragma unroll
            for (int j=0;j<8;j++){
                float wva, wvb, wvc, wvd;
                {
                    unsigned sa = (unsigned)(unsigned short)wa[j] << 16; wva = __uint_as_float(sa);
                    unsigned sb = (unsigned)(unsigned short)wb[j] << 16; wvb = __uint_as_float(sb);
                    unsigned sc = (unsigned)(unsigned short)wc[j] << 16; wvc = __uint_as_float(sc);
                    unsigned sd = (unsigned)(unsigned short)wd[j] << 16; wvd = __uint_as_float(sd);
                }
                g0 += wva*hv[j]; g1 += wvb*hv[j]; g2 += wvc*hv[j]; g3 += wvd*hv[j];
            }
        }
        float cn = sigf(g1)*c + sigf(g0)*tanhf(g2);
        float hn = sigf(g3)*tanhf(cn);
        c = cn;
        __syncthreads();           // all reads of old hs done
        hs[tid] = hn;
        outSeq[(size_t)(td*32 + b)*512 + dir*256 + tid] = hn;
        __syncthreads();           // new hs visible
        hcur = hn;
    }
    hfin[(size_t)(dir*32 + b)*256 + tid] = hcur;
    cfin[(size_t)(dir*32 + b)*256 + tid] = c;
}

// ---------------- decoder init: concat fwd/bwd finals -> parity-0 state ----------
__global__ __launch_bounds__(256) void k_decinit(const float* __restrict__ hfin,
                                                 const float* __restrict__ cfin,
                                                 bf16* __restrict__ dec_hb,
                                                 float* __restrict__ dec_c,
                                                 unsigned* __restrict__ bar)
{
    int idx = blockIdx.x*256 + threadIdx.x;       // < 49152 = 3*32*512
    if (idx == 0) *bar = 0;                       // reset grid barrier each run
    int l = idx / 16384;
    int r = idx - l*16384;
    int b = r >> 9, u = r & 511;
    int dir = u >> 8, dd = u & 255;
    size_t src = (size_t)(l*2 + dir)*8192 + b*256 + dd;
    dec_hb[idx] = __float2bfloat16(hfin[src]);    // parity 0 region, [l][b][u]
    dec_c[idx] = cfin[src];
}

// ---------------- manual grid barrier (32 co-resident blocks, agent scope) ------
// monotonic counter: no reset, no ABA. Release: __threadfence() (agent) after
// __syncthreads (stores drained per-wave by barrier's vmcnt wait). Acquire:
// __threadfence() after spin, then __syncthreads releases the block.
__device__ __forceinline__ void gbar(unsigned* bar, unsigned target)
{
    __syncthreads();
    if (threadIdx.x == 0){
        __threadfence();                                     // agent release
        __hip_atomic_fetch_add(bar, 1u, __ATOMIC_RELAXED, __HIP_MEMORY_SCOPE_AGENT);
        while (__hip_atomic_load(bar, __ATOMIC_RELAXED, __HIP_MEMORY_SCOPE_AGENT) < target)
            __builtin_amdgcn_s_sleep(2);
        __threadfence();                                     // agent acquire
    }
    __syncthreads();
}

// ---------------- decoder LSTM gate (device fn): MFMA + fused c/h update --------
__device__ __forceinline__ void dec_gate(int uc, int tid,
    const bf16* __restrict__ X, int Kx, const bf16* __restrict__ Hb,
    const bf16* __restrict__ Wih, const bf16* __restrict__ Whh,
    const float* __restrict__ bias,
    float* __restrict__ cbuf, bf16* __restrict__ hout, bf16* __restrict__ hs_out,
    float (*part)[64][32])
{
    int w = tid >> 6, lane = tid & 63;
    int n = lane & 15, quad = lane >> 4;
    int u0 = uc * 16;
    int KxT = Kx >> 5;
    int KT = KxT + 16;
    int ktpw = KT >> 2;
    const f32x4 fz = {0.f, 0.f, 0.f, 0.f};
    f32x4 acc[2][4];
    #pragma unroll
    for (int mt=0; mt<2; mt++)
        #pragma unroll
        for (int g=0; g<4; g++) acc[mt][g] = fz;
    int koff = quad * 8;
    for (int kt = w*ktpw; kt < (w+1)*ktpw; kt++){
        const bf16* asrc; const bf16* wsrc; int k0, ldk;
        if (kt < KxT){ asrc = X;  wsrc = Wih; k0 = kt << 5;          ldk = Kx;  }
        else         { asrc = Hb; wsrc = Whh; k0 = (kt - KxT) << 5;  ldk = 512; }
        bf16x8 a0 = *(const bf16x8*)(asrc + (size_t)n*ldk + k0 + koff);
        bf16x8 a1 = *(const bf16x8*)(asrc + (size_t)(16+n)*ldk + k0 + koff);
        #pragma unroll
        for (int g = 0; g < 4; g++){
            bf16x8 bv = *(const bf16x8*)(wsrc + (size_t)(g*512 + u0 + n)*ldk + k0 + koff);
            acc[0][g] = __builtin_amdgcn_mfma_f32_16x16x32_bf16(a0, bv, acc[0][g], 0, 0, 0);
            acc[1][g] = __builtin_amdgcn_mfma_f32_16x16x32_bf16(a1, bv, acc[1][g], 0, 0, 0);
        }
    }
    __syncthreads();   // prior phase's reads of part[] complete
    #pragma unroll
    for (int mt=0; mt<2; mt++)
        #pragma unroll
        for (int g=0; g<4; g++)
            #pragma unroll
            for (int r=0; r<4; r++)
                part[w][lane][(mt*4+g)*4 + r] = acc[mt][g][r];
    __syncthreads();
    for (int pi = tid; pi < 512; pi += 256){
        int b = pi >> 4, ul = pi & 15;
        int mt = b >> 4, reg = b & 3, q = (b >> 2) & 3;
        int ln = q*16 + ul;
        int u = u0 + ul;
        float gv[4];
        #pragma unroll
        for (int g=0; g<4; g++){
            int ix = (mt*4+g)*4 + reg;
            gv[g] = part[0][ln][ix] + part[1][ln][ix] + part[2][ln][ix] + part[3][ln][ix]
                  + bias[g*512 + u];
        }
        float cp = cbuf[b*512 + u];
        float cn = sigf(gv[1])*cp + sigf(gv[0])*tanhf(gv[2]);
        float hn = sigf(gv[3])*tanhf(cn);
        cbuf[b*512 + u] = cn;
        bf16 hb2 = __float2bfloat16(hn);
        hout[b*512 + u] = hb2;
        if (hs_out) hs_out[b*512 + u] = hb2;
    }
}

// ---------------- persistent decoder: all 63 steps in one regular kernel --------
// 32 blocks x 256 threads (co-resident on 256 CUs). Phases per step:
// attn(block=b) -> gbar -> gate0(block=uc) -> gbar -> gate1 -> gbar -> gate2 -> gbar
// scores use precomputed encW[s,b,:] = Wa @ enc[s,b,:]  (h.Wa.enc == h.(Wa.enc))
__global__ __launch_bounds__(256) void k_decoder(
    const bf16* __restrict__ wih0,  const bf16* __restrict__ whh0,  const float* __restrict__ bias0,
    const bf16* __restrict__ wih12, const bf16* __restrict__ whh12, const float* __restrict__ bias12,
    const float* __restrict__ encW, const float* __restrict__ enc,
    const int* __restrict__ y, const float* __restrict__ temb,
    bf16* __restrict__ dec_hb, float* __restrict__ dec_c,
    bf16* __restrict__ x0, bf16* __restrict__ Hs, unsigned* bar)
{
    int blk = blockIdx.x;     // 32
    int tid = threadIdx.x;    // 256

    __shared__ __align__(16) float partA[4][64][32];   // 32 KB, gate reduce
    __shared__ __align__(16) float hsA[512];
    __shared__ float ps2[256];
    __shared__ float psA[128];
    __shared__ float redA[1];

    for (int t = 0; t < 63; t++){
        int pp = t & 1, pn = 1 - pp;
        bf16* hbp = dec_hb + (size_t)pp*49152;
        bf16* hbn = dec_hb + (size_t)pn*49152;

        // ---- Phase A: attention + build x0 for batch b = blk ----
        {
            const bf16* htp = hbp + 32768 + blk*512;
            hsA[tid]     = b2f(htp[tid]);
            hsA[256+tid] = b2f(htp[256+tid]);
            __syncthreads();
            {   // scores: 2 threads per s, each 256-long dot against encW
                int s = tid & 127, hf = tid >> 7;
                const float* ew = encW + (size_t)(s*32 + blk)*512 + hf*256;
                const float* hv = hsA + hf*256;
                float a0 = 0.f, a1 = 0.f, a2 = 0.f, a3 = 0.f;
                for (int d = 0; d < 256; d += 4){
                    a0 += hv[d]*ew[d];     a1 += hv[d+1]*ew[d+1];
                    a2 += hv[d+2]*ew[d+2]; a3 += hv[d+3]*ew[d+3];
                }
                ps2[hf*128 + s] = (a0+a1) + (a2+a3);
            }
            __syncthreads();
            if (tid < 128) psA[tid] = ps2[tid] + ps2[128+tid];
            __syncthreads();
            if (tid < 64){
                float v = fmaxf(psA[tid], psA[tid+64]);
                #pragma unroll
                for (int o=32;o>0;o>>=1) v = fmaxf(v, __shfl_xor(v, o));
                if (tid == 0) redA[0] = v;
            }
            __syncthreads();
            float mx = redA[0];
            if (tid < 128) psA[tid] = expf(psA[tid] - mx);
            __syncthreads();
            if (tid < 64){
                float v = psA[tid] + psA[tid+64];
                #pragma unroll
                for (int o=32;o>0;o>>=1) v += __shfl_xor(v, o);
                if (tid == 0) redA[0] = 1.f/v;
            }
            __syncthreads();
            float inv = redA[0];
            float c0 = 0.f, c1 = 0.f;
            for (int s2 = 0; s2 < 128; s2++){
                float pv = psA[s2] * inv;
                const float* er = enc + (size_t)(s2*32 + blk)*512;
                c0 += pv * er[tid];
                c1 += pv * er[256 + tid];
            }
            int tok = y[blk*64 + t];
            x0[blk*1024 + tid]       = __float2bfloat16(temb[(size_t)tok*512 + tid]);
            x0[blk*1024 + 256 + tid] = __float2bfloat16(temb[(size_t)tok*512 + 256 + tid]);
            x0[blk*1024 + 512 + tid] = __float2bfloat16(c0);
            x0[blk*1024 + 768 + tid] = __float2bfloat16(c1);
        }
        gbar(bar, (unsigned)(t*4 + 1)*32);

        // ---- Phase B: decoder layer 0 gates ----
        dec_gate(blk, tid, x0, 1024, hbp, wih0, whh0, bias0,
                 dec_c, hbn, (bf16*)nullptr, partA);
        gbar(bar, (unsigned)(t*4 + 2)*32);

        // ---- Phase C: decoder layer 1 gates ----
        dec_gate(blk, tid, hbn, 512, hbp + 16384, wih12, whh12, bias12,
                 dec_c + 16384, hbn + 16384, (bf16*)nullptr, partA);
        gbar(bar, (unsigned)(t*4 + 3)*32);

        // ---- Phase D: decoder layer 2 gates (+ Hs row for logits) ----
        dec_gate(blk, tid, hbn + 16384, 512, hbp + 32768,
                 wih12 + 1048576, whh12 + 1048576, bias12 + 2048,
                 dec_c + 32768, hbn + 32768, Hs + (size_t)t*16384, partA);
        gbar(bar, (unsigned)(t*4 + 4)*32);
    }
}

// ---------------- logits: Hs[2048pad,512]bf16 @ W_out[32000,512]fp32^T + b -------
__global__ __launch_bounds__(256) void k_logits(const bf16* __restrict__ A,
                                                const float* __restrict__ W,
                                                const float* __restrict__ bias,
                                                float* __restrict__ out)
{
    __shared__ __align__(16) bf16 As[64][40];
    __shared__ __align__(16) bf16 Bs[64][40];
    int tid = threadIdx.x;
    int n0 = blockIdx.x * 64;      // 500
    int m0 = blockIdx.y * 64;      // 32
    int w = tid >> 6, lane = tid & 63;
    int wm = w & 1, wn = w >> 1;
    int q = lane >> 4, nn = lane & 15;
    const f32x4 fz = {0.f, 0.f, 0.f, 0.f};
    f32x4 acc[2][2];
    acc[0][0] = fz; acc[0][1] = fz; acc[1][0] = fz; acc[1][1] = fz;
    int mrow = tid >> 2, kq = tid & 3;
    for (int k0 = 0; k0 < 512; k0 += 32){
        __syncthreads();
        *(uint4*)(&As[mrow][kq*8]) = *(const uint4*)(A + (size_t)(m0+mrow)*512 + k0 + kq*8);
        {
            const float* wp = W + (size_t)(n0+mrow)*512 + k0 + kq*8;
            float4 w0v = *(const float4*)wp;
            float4 w1v = *(const float4*)(wp + 4);
            bf16* bp = &Bs[mrow][kq*8];
            bp[0] = __float2bfloat16(w0v.x); bp[1] = __float2bfloat16(w0v.y);
            bp[2] = __float2bfloat16(w0v.z); bp[3] = __float2bfloat16(w0v.w);
            bp[4] = __float2bfloat16(w1v.x); bp[5] = __float2bfloat16(w1v.y);
            bp[6] = __float2bfloat16(w1v.z); bp[7] = __float2bfloat16(w1v.w);
        }
        __syncthreads();
        #pragma unroll
        for (int mt=0; mt<2; mt++){
            bf16x8 av = *(const bf16x8*)(&As[wm*32 + mt*16 + nn][q*8]);
            #pragma unroll
            for (int nt=0; nt<2; nt++){
                bf16x8 bv = *(const bf16x8*)(&Bs[wn*32 + nt*16 + nn][q*8]);
                acc[mt][nt] = __builtin_amdgcn_mfma_f32_16x16x32_bf16(av, bv, acc[mt][nt], 0, 0, 0);
            }
        }
    }
    #pragma unroll
    for (int mt=0; mt<2; mt++)
        #pragma unroll
        for (int nt=0; nt<2; nt++){
            int ncol = n0 + wn*32 + nt*16 + nn;
            float biasv = bias[ncol];
            #pragma unroll
            for (int r=0; r<4; r++){
                int row = m0 + wm*32 + mt*16 + q*4 + r;
                if (row < 2016){
                    int tt = row >> 5, b = row & 31;
                    out[(size_t)(b*63 + tt)*VT_ + ncol] = acc[mt][nt][r] + biasv;
                }
            }
        }
}

extern "C" void kernel_launch(void* const* d_in, const int* in_sizes, int n_in,
                              void* d_out, int out_size, void* d_ws, size_t ws_size,
                              hipStream_t stream)
{
    (void)in_sizes; (void)n_in; (void)out_size; (void)ws_size;
    const int*   x        = (const int*)d_in[0];
    const int*   y        = (const int*)d_in[1];
    const float* src_emb  = (const float*)d_in[2];
    const float* tgt_emb  = (const float*)d_in[3];
    const float* W_ih_e0  = (const float*)d_in[4];
    const float* W_hh_e0  = (const float*)d_in[5];
    const float* b_e0     = (const float*)d_in[6];
    const float* W_ih_e12 = (const float*)d_in[7];
    const float* W_hh_e12 = (const float*)d_in[8];
    const float* b_e12    = (const float*)d_in[9];
    const float* W_ih_d0  = (const float*)d_in[10];
    const float* W_hh_d0  = (const float*)d_in[11];
    const float* b_d0     = (const float*)d_in[12];
    const float* W_ih_d12 = (const float*)d_in[13];
    const float* W_hh_d12 = (const float*)d_in[14];
    const float* b_d12    = (const float*)d_in[15];
    const float* W_a      = (const float*)d_in[16];
    const float* W_out    = (const float*)d_in[17];
    const float* b_out    = (const float*)d_in[18];

    char* p = (char*)d_ws;
    float* encA   = (float*)p;  p += (size_t)128*32*512*4;      // 8 MB
    float* encB   = (float*)p;  p += (size_t)128*32*512*4;      // 8 MB
    float* xg     = (float*)p;  p += (size_t)2*128*32*1024*4;   // 32 MB
    float* hfin   = (float*)p;  p += (size_t)3*2*32*256*4;
    float* cfin   = (float*)p;  p += (size_t)3*2*32*256*4;
    bf16*  dec_hb = (bf16*)p;   p += (size_t)2*3*32*512*2;      // [parity][l][b][u]
    float* dec_c  = (float*)p;  p += (size_t)3*32*512*4;        // [l][b][u]
    bf16*  x0     = (bf16*)p;   p += (size_t)32*1024*2;
    bf16*  Hs     = (bf16*)p;   p += (size_t)2048*512*2;        // 2016 rows + pad
    float* encW   = (float*)p;  p += (size_t)128*32*512*4;      // 8 MB  (Wa @ enc)
    unsigned* bar = (unsigned*)p; p += 256;                     // grid barrier counter
    bf16*  wb16   = (bf16*)p;   p += (size_t)8912896*2;         // converted weights

    bf16* whh_e0_b  = wb16;                 // 524288  = 2*1024*256
    bf16* whh_e12_b = wb16 + 524288;        // 1048576 = 2*2*1024*256
    bf16* wih_d0_b  = wb16 + 1572864;       // 2097152 = 2048*1024
    bf16* whh_d0_b  = wb16 + 3670016;       // 1048576 = 2048*512
    bf16* wih_d12_b = wb16 + 4718592;       // 2097152 = 2*2048*512
    bf16* whh_d12_b = wb16 + 6815744;       // 2097152 = 2*2048*512

    k_cvt<<<512,  256, 0, stream>>>(W_hh_e0,  whh_e0_b,  524288);
    k_cvt<<<1024, 256, 0, stream>>>(W_hh_e12, whh_e12_b, 1048576);
    k_cvt<<<2048, 256, 0, stream>>>(W_ih_d0,  wih_d0_b,  2097152);
    k_cvt<<<1024, 256, 0, stream>>>(W_hh_d0,  whh_d0_b,  1048576);
    k_cvt<<<2048, 256, 0, stream>>>(W_ih_d12, wih_d12_b, 2097152);
    k_cvt<<<2048, 256, 0, stream>>>(W_hh_d12, whh_d12_b, 2097152);

    k_embed<<<4096, 256, 0, stream>>>(x, src_emb, encA);

    // encoder layer 0 (in=256)
    k_xgemm<<<dim3(16,64,2), 256, 0, stream>>>(encA, 256, 256, W_ih_e0, b_e0, xg, 1024);
    k_encscan<<<64, 256, 0, stream>>>(xg, whh_e0_b, encB, hfin, cfin);
    // encoder layer 1 (in=512)
    k_xgemm<<<dim3(16,64,2), 256, 0, stream>>>(encB, 512, 512, W_ih_e12, b_e12, xg, 1024);
    k_encscan<<<64, 256, 0, stream>>>(xg, whh_e12_b, encA, hfin + 16384, cfin + 16384);
    // encoder layer 2 (in=512)
    k_xgemm<<<dim3(16,64,2), 256, 0, stream>>>(encA, 512, 512, W_ih_e12 + 2*1024*512,
                                               b_e12 + 2048, xg, 1024);
    k_encscan<<<64, 256, 0, stream>>>(xg, whh_e12_b + 524288, encB,
                                      hfin + 32768, cfin + 32768);

    // encW[s*32+b][d] = sum_e enc[s*32+b][e] * Wa[d][e]   (hoists h@Wa out of loop)
    k_xgemm<<<dim3(8,64,1), 256, 0, stream>>>(encB, 512, 512, W_a,
                                              (const float*)nullptr, encW, 512);

    k_decinit<<<192, 256, 0, stream>>>(hfin, cfin, dec_hb, dec_c, bar);

    // persistent decoder (regular launch; manual agent-scope grid barrier)
    k_decoder<<<32, 256, 0, stream>>>(wih_d0_b, whh_d0_b, b_d0,
                                      wih_d12_b, whh_d12_b, b_d12,
                                      encW, encB, y, tgt_emb,
                                      dec_hb, dec_c, x0, Hs, bar);

    k_logits<<<dim3(500,32), 256, 0, stream>>>(Hs, W_out, b_out, (float*)d_out);
}